// Round 16
// baseline (62.069 us; speedup 1.0000x reference)
//
#include <hip/hip_runtime.h>
#include <cstddef>

#define T_DIM 30000
#define M_DIM 23
#define NJ    92
#define TILE  64      // output timesteps per conv block
#define STR   184     // Yt stride in bf16 units (368 B)
#define SUBS  25      // sub LDS stride
#define XP4   377     // reduce LDS pitch in float4
#define WPS   144     // wpadT per-g stride (x in [-16,127])

typedef short bf16x8 __attribute__((ext_vector_type(8)));
typedef float f32x4  __attribute__((ext_vector_type(4)));

__device__ __forceinline__ unsigned short f2bf(float f) {
    unsigned int u = __float_as_uint(f);
    return (unsigned short)((u + 0x7fffu + ((u >> 16) & 1u)) >> 16);
}

// ---- Kernel B: X (T,1500) fp32 -> Yb (T,92) bf16 ; Yb[t,j] = sum_{n%92==j} X[t,n]
// High-TLP variant: 2 rows per 128-thread block (12 KB LDS -> ~13 blocks/CU).
__global__ __launch_bounds__(128) void reduce_k(const float* __restrict__ X,
                                                unsigned short* __restrict__ Yb) {
    __shared__ __align__(16) float4 Xs[2 * XP4];   // 12064 B

    const int tid = threadIdx.x;
    const int tb  = blockIdx.x * 2;                // 15000 blocks x 2 rows

    const float4* Xg = reinterpret_cast<const float4*>(X) + (size_t)tb * 375;
    #pragma unroll
    for (int it = 0; it < 6; ++it) {
        int i = tid + 128 * it;
        if (i < 750) {
            int r = (i >= 375) ? 1 : 0;
            int pos = i - r * 375;
            Xs[r * XP4 + pos] = Xg[i];
        }
    }
    __syncthreads();

    if (tid < 46) {
        int r = tid / 23;
        int q = tid - 23 * r;
        const float4* row = &Xs[r * XP4];
        float4 s = make_float4(0.f, 0.f, 0.f, 0.f);
        #pragma unroll
        for (int k = 0; k < 16; ++k) {
            float4 v = row[q + 23 * k];
            s.x += v.x; s.y += v.y; s.z += v.z; s.w += v.w;
        }
        if (q < 7) {
            float4 v = row[q + 23 * 16];
            s.x += v.x; s.y += v.y; s.z += v.z; s.w += v.w;
        }
        ushort4 o;
        o.x = f2bf(s.x); o.y = f2bf(s.y); o.z = f2bf(s.z); o.w = f2bf(s.w);
        reinterpret_cast<ushort4*>(Yb)[(size_t)(tb + r) * 23 + q] = o;
    }
}

// ---- Kernel C: MFMA Toeplitz conv + tree cascade (exact R12/R14 structure).
__global__ __launch_bounds__(512, 2) void conv_tree_k(
    const unsigned short* __restrict__ Yb,
    const float* __restrict__ Tau,
    const float* __restrict__ Delta,
    const float* __restrict__ W,
    const float* __restrict__ Vo,
    const float* __restrict__ C,
    const float* __restrict__ Theta,
    float* __restrict__ out)
{
    __shared__ __align__(16) unsigned short Yt[NJ * STR];  // 33856 B, col-major
    __shared__ __align__(16) float wpadT[4 * WPS];         // 2304 B
    __shared__ float sub[TILE * SUBS];                     // 6400 B
    __shared__ float sTheta[M_DIM];
    __shared__ float sExpC[M_DIM];

    const int tid = threadIdx.x;
    const int t0  = blockIdx.x * TILE;
    const int l   = tid & 63;

    // --- padded weight table: wpadT[g*WPS + (x+16)] = wk(g,x)*W[g], x in [-16,127]
    {
        float eD = __expf(Delta[0]);
        for (int i = tid; i < 4 * WPS; i += 512) {
            int g = i / WPS;
            int x = (i - g * WPS) - 16;
            float val = 0.f;
            if (x >= 0 && x <= 100) {
                float tt  = fmaxf((float)x - eD, 0.f);
                float tau = __expf(Tau[g]);
                float tf  = tt / tau;
                float fast = tf * __expf(-tf);
                float kv;
                if (g < 2) {
                    float ts = tt / (tau * 2.8f + 10.4f);
                    kv = (fast + ts * __expf(-ts) * 0.3f) * (1.0f / 1.3f);
                } else {
                    kv = fast;
                }
                val = kv * W[g];
            }
            wpadT[i] = val;
        }
    }
    if (tid < M_DIM) {
        sTheta[tid] = Theta[tid];
        sExpC[tid]  = __expf(C[tid]);
    }
    __syncthreads();

    // --- stage Yb rows [t0-50, t0+126) transposed into Yt[col'][r] (bf16),
    //     col' = (c>>2) + 23*(c&3); row pairs packed into dwords. 88 pairs.
    {
        unsigned int* Yw = reinterpret_cast<unsigned int*>(Yt);
        for (int i = tid; i < 88 * 23; i += 512) {
            int rp = i / 23;
            int q  = i - rp * 23;
            int g0 = t0 - 50 + 2 * rp;
            ushort4 ra = make_ushort4(0, 0, 0, 0);
            ushort4 rb = make_ushort4(0, 0, 0, 0);
            if ((unsigned)g0       < (unsigned)T_DIM) ra = reinterpret_cast<const ushort4*>(Yb)[(size_t)g0 * 23 + q];
            if ((unsigned)(g0 + 1) < (unsigned)T_DIM) rb = reinterpret_cast<const ushort4*>(Yb)[(size_t)(g0 + 1) * 23 + q];
            Yw[(q     ) * 92 + rp] = (unsigned)ra.x | ((unsigned)rb.x << 16);
            Yw[(q + 23) * 92 + rp] = (unsigned)ra.y | ((unsigned)rb.y << 16);
            Yw[(q + 46) * 92 + rp] = (unsigned)ra.z | ((unsigned)rb.z << 16);
            Yw[(q + 69) * 92 + rp] = (unsigned)ra.w | ((unsigned)rb.w << 16);
        }
    }

    // --- A-fragments from wpadT (overlaps staging). frag (g,kk): lane l elem j ->
    // A_g[i,k] = Wpad_g[k-i], i = l&15, k = kk*32 + (l>>4)*8 + j.
    const int n  = l & 15;
    const int kq = (l >> 4) << 3;
    uint4 af[16];
    #pragma unroll
    for (int g = 0; g < 4; ++g) {
        const float* wp = &wpadT[g * WPS + 16 - n + kq];
        #pragma unroll
        for (int kk = 0; kk < 4; ++kk) {
            const float* wk8 = wp + kk * 32;
            unsigned int d[4];
            #pragma unroll
            for (int p = 0; p < 4; ++p) {
                unsigned short lo = f2bf(wk8[2 * p]);
                unsigned short hi = f2bf(wk8[2 * p + 1]);
                d[p] = (unsigned)lo | ((unsigned)hi << 16);
            }
            af[g * 4 + kk] = make_uint4(d[0], d[1], d[2], d[3]);
        }
    }

    const int wave = tid >> 6;            // 0..7
    const int dt   = (wave & 3) * 16;     // t-subtile
    const int nt   = wave >> 2;           // m-tile
    const int m    = nt * 16 + n;
    const bool mvalid = (m < M_DIM);
    const int mc   = mvalid ? m : 0;

    __syncthreads();

    f32x4 acc = {0.f, 0.f, 0.f, 0.f};
    #pragma unroll
    for (int g = 0; g < 4; ++g) {
        int a  = (3 * ((g - mc) & 3)) & 3;
        int j  = mc + 23 * a;
        int cp = (j >> 2) + 23 * g;
        const unsigned short* colp = &Yt[cp * STR + dt + kq];

        bf16x8 b0 = *reinterpret_cast<const bf16x8*>(colp);
        acc = __builtin_amdgcn_mfma_f32_16x16x32_bf16(__builtin_bit_cast(bf16x8, af[g*4+0]), b0, acc, 0, 0, 0);
        bf16x8 b1 = *reinterpret_cast<const bf16x8*>(colp + 32);
        acc = __builtin_amdgcn_mfma_f32_16x16x32_bf16(__builtin_bit_cast(bf16x8, af[g*4+1]), b1, acc, 0, 0, 0);
        bf16x8 b2 = *reinterpret_cast<const bf16x8*>(colp + 64);
        acc = __builtin_amdgcn_mfma_f32_16x16x32_bf16(__builtin_bit_cast(bf16x8, af[g*4+2]), b2, acc, 0, 0, 0);
        bf16x8 b3 = *reinterpret_cast<const bf16x8*>(colp + 96);
        acc = __builtin_amdgcn_mfma_f32_16x16x32_bf16(__builtin_bit_cast(bf16x8, af[g*4+3]), b3, acc, 0, 0, 0);
    }

    // epilogue: D col = l&15 (m), row = (l>>4)*4 + r -> t_local = dt + row
    if (mvalid) {
        int i0 = (l >> 4) * 4;
        #pragma unroll
        for (int r = 0; r < 4; ++r)
            sub[(dt + i0 + r) * SUBS + m] = acc[r];
    }
    __syncthreads();

    // --- tree cascade, one thread per timestep
    if (tid < TILE) {
        int t = t0 + tid;
        if (t < T_DIM) {
            const float* s = &sub[tid * SUBS];
            float o[M_DIM];
            #pragma unroll
            for (int mm = 11; mm < 23; ++mm) {
                float x = s[mm] - sTheta[mm];
                o[mm] = sExpC[mm] / (1.f + __expf(-x));
            }
            #pragma unroll
            for (int rr = 10; rr >= 0; --rr) {
                float x = s[rr] + o[2 * rr + 1] + o[2 * rr + 2] - sTheta[rr];
                o[rr] = sExpC[rr] / (1.f + __expf(-x));
            }
            out[t] = o[0] + Vo[0];
        }
    }
}

extern "C" void kernel_launch(void* const* d_in, const int* in_sizes, int n_in,
                              void* d_out, int out_size, void* d_ws, size_t ws_size,
                              hipStream_t stream) {
    const float* X     = (const float*)d_in[0];
    const float* Vo    = (const float*)d_in[1];
    const float* Tau   = (const float*)d_in[2];
    const float* Delta = (const float*)d_in[3];
    const float* W     = (const float*)d_in[4];
    const float* C     = (const float*)d_in[5];
    const float* Theta = (const float*)d_in[6];
    float* out = (float*)d_out;
    unsigned short* Yb = (unsigned short*)d_ws;   // T_DIM * 92 bf16 = 5.52 MB

    reduce_k<<<T_DIM / 2, 128, 0, stream>>>(X, Yb);
    // DECOMPOSITION PROBE: conv launched 3x (idempotent). Baseline R14 = 42.6.
    // conv = (total - 43.6) / 2.  H1 -> total ~60-62; H2 -> total ~47-49.
    conv_tree_k<<<(T_DIM + TILE - 1) / TILE, 512, 0, stream>>>(
        Yb, Tau, Delta, W, Vo, C, Theta, out);
    conv_tree_k<<<(T_DIM + TILE - 1) / TILE, 512, 0, stream>>>(
        Yb, Tau, Delta, W, Vo, C, Theta, out);
    conv_tree_k<<<(T_DIM + TILE - 1) / TILE, 512, 0, stream>>>(
        Yb, Tau, Delta, W, Vo, C, Theta, out);
}

// Round 17
// 38.387 us; speedup vs baseline: 1.6169x; 1.6169x over previous
//
#include <hip/hip_runtime.h>
#include <cstddef>

#define T_DIM 30000
#define M_DIM 23
#define NJ    92
#define TILE  64      // output timesteps per conv block
#define STR   184     // Yt stride in bf16 units (368 B)
#define SUBS  25      // sub LDS stride
#define XP4   377     // reduce LDS pitch in float4

typedef short bf16x8 __attribute__((ext_vector_type(8)));
typedef float f32x4  __attribute__((ext_vector_type(4)));

__device__ __forceinline__ unsigned short f2bf(float f) {
    unsigned int u = __float_as_uint(f);
    return (unsigned short)((u + 0x7fffu + ((u >> 16) & 1u)) >> 16);
}

// ---- Kernel B: X (T,1500) fp32 -> Yb (T,92) bf16 ; Yb[t,j] = sum_{n%92==j} X[t,n]
// High-TLP: 2 rows per 128-thread block. Block 0 additionally writes the
// Toeplitz A-fragment table (1024 x 16B) used by the conv kernel.
__global__ __launch_bounds__(128) void reduce_k(const float* __restrict__ X,
                                                const float* __restrict__ Tau,
                                                const float* __restrict__ Delta,
                                                const float* __restrict__ W,
                                                unsigned short* __restrict__ Yb,
                                                unsigned int* __restrict__ afrag) {
    __shared__ __align__(16) float4 Xs[2 * XP4];   // 12064 B

    const int tid = threadIdx.x;
    const int tb  = blockIdx.x * 2;                // 15000 blocks x 2 rows

    const float4* Xg = reinterpret_cast<const float4*>(X) + (size_t)tb * 375;
    #pragma unroll
    for (int it = 0; it < 6; ++it) {
        int i = tid + 128 * it;
        if (i < 750) {
            int r = (i >= 375) ? 1 : 0;
            int pos = i - r * 375;
            Xs[r * XP4 + pos] = Xg[i];
        }
    }
    __syncthreads();

    if (tid < 46) {
        int r = tid / 23;
        int q = tid - 23 * r;
        const float4* row = &Xs[r * XP4];
        float4 s = make_float4(0.f, 0.f, 0.f, 0.f);
        #pragma unroll
        for (int k = 0; k < 16; ++k) {
            float4 v = row[q + 23 * k];
            s.x += v.x; s.y += v.y; s.z += v.z; s.w += v.w;
        }
        if (q < 7) {
            float4 v = row[q + 23 * 16];
            s.x += v.x; s.y += v.y; s.z += v.z; s.w += v.w;
        }
        ushort4 o;
        o.x = f2bf(s.x); o.y = f2bf(s.y); o.z = f2bf(s.z); o.w = f2bf(s.w);
        reinterpret_cast<ushort4*>(Yb)[(size_t)(tb + r) * 23 + q] = o;
    }

    // block 0: Toeplitz A-fragments. A_g[i,k] = Wpad_g[k-i]; frag (g,kk):
    // lane l elem j -> i = l&15, k = kk*32 + (l>>4)*8 + j; x = k - i.
    if (blockIdx.x == 0) {
        for (int item = tid; item < 1024; item += 128) {
            int f = item >> 6;
            int l = item & 63;
            int g = f >> 2, kk = f & 3;
            float eD  = __expf(Delta[0]);
            float tau = __expf(Tau[g]);
            float wg  = W[g];
            unsigned short vals[8];
            #pragma unroll
            for (int j = 0; j < 8; ++j) {
                int x = kk * 32 + ((l >> 4) << 3) + j - (l & 15);
                float val = 0.f;
                if (x >= 0 && x <= 100) {
                    float tt  = fmaxf((float)x - eD, 0.f);
                    float tf  = tt / tau;
                    float fast = tf * __expf(-tf);
                    float kv;
                    if (g < 2) {
                        float ts = tt / (tau * 2.8f + 10.4f);
                        kv = (fast + ts * __expf(-ts) * 0.3f) * (1.0f / 1.3f);
                    } else {
                        kv = fast;
                    }
                    val = kv * wg;
                }
                vals[j] = f2bf(val);
            }
            uint4 o;
            o.x = (unsigned)vals[0] | ((unsigned)vals[1] << 16);
            o.y = (unsigned)vals[2] | ((unsigned)vals[3] << 16);
            o.z = (unsigned)vals[4] | ((unsigned)vals[5] << 16);
            o.w = (unsigned)vals[6] | ((unsigned)vals[7] << 16);
            reinterpret_cast<uint4*>(afrag)[f * 64 + l] = o;
        }
    }
}

// ---- Kernel C: MFMA Toeplitz conv + tree cascade (R9 structure: global af).
// 512 threads = 8 waves: wave -> (dt = (w&3)*16, nt = w>>2).
__global__ __launch_bounds__(512, 4) void conv_tree_k(
    const unsigned short* __restrict__ Yb,
    const unsigned int* __restrict__ afrag,
    const float* __restrict__ Vo,
    const float* __restrict__ C,
    const float* __restrict__ Theta,
    float* __restrict__ out)
{
    __shared__ __align__(16) unsigned short Yt[NJ * STR];  // 33856 B, col-major
    __shared__ float sub[TILE * SUBS];                     // 6400 B
    __shared__ float sTheta[M_DIM];
    __shared__ float sExpC[M_DIM];

    const int tid = threadIdx.x;
    const int t0  = blockIdx.x * TILE;

    if (tid < M_DIM) {
        sTheta[tid] = Theta[tid];
        sExpC[tid]  = __expf(C[tid]);
    }

    // --- stage Yb rows [t0-50, t0+126) transposed into Yt[col'][r] (bf16),
    //     col' = (c>>2) + 23*(c&3); row pairs packed into dwords. 88 pairs.
    {
        unsigned int* Yw = reinterpret_cast<unsigned int*>(Yt);
        for (int i = tid; i < 88 * 23; i += 512) {
            int rp = i / 23;
            int q  = i - rp * 23;
            int g0 = t0 - 50 + 2 * rp;
            ushort4 ra = make_ushort4(0, 0, 0, 0);
            ushort4 rb = make_ushort4(0, 0, 0, 0);
            if ((unsigned)g0       < (unsigned)T_DIM) ra = reinterpret_cast<const ushort4*>(Yb)[(size_t)g0 * 23 + q];
            if ((unsigned)(g0 + 1) < (unsigned)T_DIM) rb = reinterpret_cast<const ushort4*>(Yb)[(size_t)(g0 + 1) * 23 + q];
            Yw[(q     ) * 92 + rp] = (unsigned)ra.x | ((unsigned)rb.x << 16);
            Yw[(q + 23) * 92 + rp] = (unsigned)ra.y | ((unsigned)rb.y << 16);
            Yw[(q + 46) * 92 + rp] = (unsigned)ra.z | ((unsigned)rb.z << 16);
            Yw[(q + 69) * 92 + rp] = (unsigned)ra.w | ((unsigned)rb.w << 16);
        }
    }

    const int l    = tid & 63;
    const int wave = tid >> 6;            // 0..7
    const int dt   = (wave & 3) * 16;     // t-subtile
    const int nt   = wave >> 2;           // m-tile (0: m 0-15, 1: m 16-22)
    const int n    = l & 15;
    const int m    = nt * 16 + n;
    const bool mvalid = (m < M_DIM);
    const int mc   = mvalid ? m : 0;
    const int kq   = (l >> 4) << 3;       // k-slot base: 0,8,16,24

    __syncthreads();

    f32x4 acc = {0.f, 0.f, 0.f, 0.f};
    const uint4* AF = reinterpret_cast<const uint4*>(afrag);

    #pragma unroll
    for (int g = 0; g < 4; ++g) {
        // column j: j%23 == mc, j%4 == g -> a = 3*(g-mc) mod 4; col' = (j>>2) + 23g
        int a  = (3 * ((g - mc) & 3)) & 3;
        int j  = mc + 23 * a;
        int cp = (j >> 2) + 23 * g;
        const unsigned short* colp = &Yt[cp * STR + dt + kq];

        uint4 a0 = AF[(g * 4 + 0) * 64 + l];
        uint4 a1 = AF[(g * 4 + 1) * 64 + l];
        uint4 a2 = AF[(g * 4 + 2) * 64 + l];
        uint4 a3 = AF[(g * 4 + 3) * 64 + l];

        bf16x8 b0 = *reinterpret_cast<const bf16x8*>(colp);
        acc = __builtin_amdgcn_mfma_f32_16x16x32_bf16(__builtin_bit_cast(bf16x8, a0), b0, acc, 0, 0, 0);
        bf16x8 b1 = *reinterpret_cast<const bf16x8*>(colp + 32);
        acc = __builtin_amdgcn_mfma_f32_16x16x32_bf16(__builtin_bit_cast(bf16x8, a1), b1, acc, 0, 0, 0);
        bf16x8 b2 = *reinterpret_cast<const bf16x8*>(colp + 64);
        acc = __builtin_amdgcn_mfma_f32_16x16x32_bf16(__builtin_bit_cast(bf16x8, a2), b2, acc, 0, 0, 0);
        bf16x8 b3 = *reinterpret_cast<const bf16x8*>(colp + 96);
        acc = __builtin_amdgcn_mfma_f32_16x16x32_bf16(__builtin_bit_cast(bf16x8, a3), b3, acc, 0, 0, 0);
    }

    // epilogue: D col = l&15, row = (l>>4)*4 + r  ->  t_local = dt + row, m-col
    if (mvalid) {
        int i0 = (l >> 4) * 4;
        #pragma unroll
        for (int r = 0; r < 4; ++r)
            sub[(dt + i0 + r) * SUBS + m] = acc[r];
    }
    __syncthreads();

    // --- tree cascade, one thread per timestep
    if (tid < TILE) {
        int t = t0 + tid;
        if (t < T_DIM) {
            const float* s = &sub[tid * SUBS];
            float o[M_DIM];
            #pragma unroll
            for (int mm = 11; mm < 23; ++mm) {
                float x = s[mm] - sTheta[mm];
                o[mm] = sExpC[mm] / (1.f + __expf(-x));
            }
            #pragma unroll
            for (int rr = 10; rr >= 0; --rr) {
                float x = s[rr] + o[2 * rr + 1] + o[2 * rr + 2] - sTheta[rr];
                o[rr] = sExpC[rr] / (1.f + __expf(-x));
            }
            out[t] = o[0] + Vo[0];
        }
    }
}

extern "C" void kernel_launch(void* const* d_in, const int* in_sizes, int n_in,
                              void* d_out, int out_size, void* d_ws, size_t ws_size,
                              hipStream_t stream) {
    const float* X     = (const float*)d_in[0];
    const float* Vo    = (const float*)d_in[1];
    const float* Tau   = (const float*)d_in[2];
    const float* Delta = (const float*)d_in[3];
    const float* W     = (const float*)d_in[4];
    const float* C     = (const float*)d_in[5];
    const float* Theta = (const float*)d_in[6];
    float* out = (float*)d_out;

    unsigned short* Yb  = (unsigned short*)d_ws;                                  // 5.52 MB
    unsigned int* afrag = (unsigned int*)((char*)d_ws + (size_t)T_DIM * NJ * 2);  // 16 KB

    reduce_k<<<T_DIM / 2, 128, 0, stream>>>(X, Tau, Delta, W, Yb, afrag);
    conv_tree_k<<<(T_DIM + TILE - 1) / TILE, 512, 0, stream>>>(
        Yb, afrag, Vo, C, Theta, out);
}